// Round 4
// baseline (88.832 us; speedup 1.0000x reference)
//
#include <hip/hip_runtime.h>
#include <cfloat>
#include <cmath>

// x[B,W,L], shapelets[N,L], cls_w[1,N], cls_b[1]
constexpr int B = 64;
constexpr int W = 256;
constexpr int N = 128;
constexpr int L = 64;
constexpr int NC = 16;        // window-chunks per batch element (R4: back to 16)
constexpr int WPB = W / NC;   // 16 windows per block
constexpr int WAVES_PER_B = NC * 4;  // 64 arriving waves per batch element

// Arrival counters, zero-initialized at module load (NOT in the poisoned
// workspace); the last wave restores 0 for the next graph replay. R2 verified
// the sc1-store + relaxed-agent-atomic protocol under graph capture + rocprof
// counter replay.
__device__ int g_cnt[B];

// VALU-pipe cross-lane add (DPP), avoiding the DS pipe entirely.
// CTRL: 0xB1 = quad_perm xor1, 0x4E = quad_perm xor2,
//       0x141 = row_half_mirror (xor-4 class), 0x140 = row_mirror (xor-8).
template <int CTRL>
__device__ __forceinline__ float dpp_add(float v) {
  return v + __int_as_float(__builtin_amdgcn_update_dpp(
                 0, __float_as_int(v), CTRL, 0xF, 0xF, true));
}

// ---------------------------------------------------------------------------
// FUSED kernel, round 4.
// R3 post-mortem: 2048 blocks (8/CU) LOST 9us vs 1024 (4/CU) -> the kernel is
// NOT wave-starved; it pays per-block fixed cost. So: revert to the
// twice-proven NC=16 geometry and attack the per-block epilogue instead.
//
// Epilogue redesign (this round's change):
//  - NO barriers after the hot loop. Each wave: fence(release,"workgroup")
//    (= s_waitcnt vmcnt(0), zero cache-maintenance ops — R1 taught us agent
//    fences emit a 4MiB L2 writeback walk; workgroup release does not) ->
//    lane0 relaxed agent fetch_add -> readfirstlane broadcast -> non-last
//    waves RETIRE. Waves never wait on sibling waves' arrival RTT.
//  - The 64th wave alone runs the classifier head for its b: 2 shapelets per
//    lane, coalesced agent loads of part, ||s||^2 recomputed from L2-hot shp
//    (q-tree deleted from all blocks).
// Correctness: every wave's sc1 part-stores are at the agent-coherent point
// (MALL) before its arrival add is issued (vmcnt(0) between them); the tail
// wave reads part with agent-scope loads (bypass stale L1/L2). Same
// happens-before chain as R2, per-wave instead of per-block.
// grid = B*NC = 1024, block = 256 (4 blocks/CU).
// ---------------------------------------------------------------------------
__global__ __launch_bounds__(256)
void shapelet_fused_kernel(const float* __restrict__ x,
                           const float* __restrict__ shp,
                           const float* __restrict__ cls_w,
                           const float* __restrict__ cls_b,
                           float* __restrict__ part,
                           float* __restrict__ out) {
  __shared__ float xs[WPB * L];   // 4 KB
  __shared__ float xnorm_s[WPB];

  const int b = blockIdx.x >> 4;
  const int c = blockIdx.x & 15;
  const int tid = threadIdx.x;
  const int oct = tid & 7;        // eighth-of-row owned by this lane
  const int grp = tid >> 3;       // 0..31 -> shapelets 4*grp..4*grp+3
  const int n0 = grp * 4;

  // --- Issue shapelet loads FIRST so their latency overlaps x-staging.
  const float4* g0 = (const float4*)(shp + (size_t)(n0 + 0) * L + oct * 8);
  const float4* g1 = (const float4*)(shp + (size_t)(n0 + 1) * L + oct * 8);
  const float4* g2 = (const float4*)(shp + (size_t)(n0 + 2) * L + oct * 8);
  const float4* g3 = (const float4*)(shp + (size_t)(n0 + 3) * L + oct * 8);
  const float4 s0a = g0[0], s0b = g0[1];
  const float4 s1a = g1[0], s1b = g1[1];
  const float4 s2a = g2[0], s2b = g2[1];
  const float4 s3a = g3[0], s3b = g3[1];

  // --- Stage x[b, c*16:(c+1)*16, :]: one float4/thread; ||x_w||^2 via a
  // 16-lane DPP reduction — zero DS-pipe swizzles.
  {
    const float4* xg =
        (const float4*)(x + ((size_t)b * W + (size_t)c * WPB) * L);
    float4 v = xg[tid];
    ((float4*)xs)[tid] = v;
    float p = v.x * v.x + v.y * v.y + v.z * v.z + v.w * v.w;
    p = dpp_add<0xB1>(p);    // xor1 (quad)
    p = dpp_add<0x4E>(p);    // xor2 (quad)
    p = dpp_add<0x141>(p);   // 4<->8 within row of 16
    p = dpp_add<0x140>(p);   // mirror row of 16
    if ((tid & 15) == 0) xnorm_s[tid >> 4] = p;
  }

  __syncthreads();   // the ONLY barrier in the kernel (staging visibility)

  // --- min over all 16 windows of (xnorm_w - 2*dot(x_w, s_n)).
  // Hot loop UNCHANGED from the proven 68.8us version (spill-free, DS/VALU
  // balanced, SQ_LDS_BANK_CONFLICT = 0).
  float best0 = FLT_MAX, best1 = FLT_MAX, best2 = FLT_MAX, best3 = FLT_MAX;
  for (int w = 0; w < WPB; ++w) {
    const float4* xr = (const float4*)(xs + (size_t)w * L + oct * 8);
    const float4 xa = xr[0];
    const float4 xb = xr[1];

    float d0 = xa.x * s0a.x + xa.y * s0a.y;
    float d1 = xa.x * s1a.x + xa.y * s1a.y;
    float d2 = xa.x * s2a.x + xa.y * s2a.y;
    float d3 = xa.x * s3a.x + xa.y * s3a.y;
    d0 = fmaf(xa.z, s0a.z, d0); d0 = fmaf(xa.w, s0a.w, d0);
    d1 = fmaf(xa.z, s1a.z, d1); d1 = fmaf(xa.w, s1a.w, d1);
    d2 = fmaf(xa.z, s2a.z, d2); d2 = fmaf(xa.w, s2a.w, d2);
    d3 = fmaf(xa.z, s3a.z, d3); d3 = fmaf(xa.w, s3a.w, d3);
    d0 = fmaf(xb.x, s0b.x, d0); d0 = fmaf(xb.y, s0b.y, d0);
    d1 = fmaf(xb.x, s1b.x, d1); d1 = fmaf(xb.y, s1b.y, d1);
    d2 = fmaf(xb.x, s2b.x, d2); d2 = fmaf(xb.y, s2b.y, d2);
    d3 = fmaf(xb.x, s3b.x, d3); d3 = fmaf(xb.y, s3b.y, d3);
    d0 = fmaf(xb.z, s0b.z, d0); d0 = fmaf(xb.w, s0b.w, d0);
    d1 = fmaf(xb.z, s1b.z, d1); d1 = fmaf(xb.w, s1b.w, d1);
    d2 = fmaf(xb.z, s2b.z, d2); d2 = fmaf(xb.w, s2b.w, d2);
    d3 = fmaf(xb.z, s3b.z, d3); d3 = fmaf(xb.w, s3b.w, d3);

    d0 = dpp_add<0xB1>(d0);  d1 = dpp_add<0xB1>(d1);
    d2 = dpp_add<0xB1>(d2);  d3 = dpp_add<0xB1>(d3);
    d0 = dpp_add<0x4E>(d0);  d1 = dpp_add<0x4E>(d1);
    d2 = dpp_add<0x4E>(d2);  d3 = dpp_add<0x4E>(d3);
    d0 = dpp_add<0x141>(d0); d1 = dpp_add<0x141>(d1);
    d2 = dpp_add<0x141>(d2); d3 = dpp_add<0x141>(d3);

    const float xn = xnorm_s[w];
    best0 = fminf(best0, fmaf(-2.f, d0, xn));
    best1 = fminf(best1, fmaf(-2.f, d1, xn));
    best2 = fminf(best2, fmaf(-2.f, d2, xn));
    best3 = fminf(best3, fmaf(-2.f, d3, xn));
  }

  // --- oct-leader writes 4 chunk-mins (xnorm - 2dot; ||s||^2 added in the
  // tail) as AGENT-scope (sc1) write-through stores (R2-verified protocol).
  if (oct == 0) {
    float* p = part + ((size_t)b * NC + c) * N + n0;
    __hip_atomic_store(p + 0, best0, __ATOMIC_RELAXED,
                       __HIP_MEMORY_SCOPE_AGENT);
    __hip_atomic_store(p + 1, best1, __ATOMIC_RELAXED,
                       __HIP_MEMORY_SCOPE_AGENT);
    __hip_atomic_store(p + 2, best2, __ATOMIC_RELAXED,
                       __HIP_MEMORY_SCOPE_AGENT);
    __hip_atomic_store(p + 3, best3, __ATOMIC_RELAXED,
                       __HIP_MEMORY_SCOPE_AGENT);
  }

  // --- Per-wave arrival, no barrier. Workgroup-scope release fence emits
  // s_waitcnt vmcnt(0) lgkmcnt(0) and NO cache-maintenance (the R1 failure
  // was agent-scope fence = buffer_wbl2). Hardware-wise that retires this
  // wave's sc1 write-through stores at the agent-coherent point before the
  // arrival add below is issued — identical mechanism to R2's __syncthreads,
  // minus the barrier.
  __builtin_amdgcn_fence(__ATOMIC_RELEASE, "workgroup");
  int done = 0;
  if ((tid & 63) == 0)
    done = __hip_atomic_fetch_add(&g_cnt[b], 1, __ATOMIC_RELAXED,
                                  __HIP_MEMORY_SCOPE_AGENT);
  done = __builtin_amdgcn_readfirstlane(done);
  if (done != WAVES_PER_B - 1) return;   // non-last waves retire immediately

  // ======================== 1-wave classifier head =========================
  // This wave observed count==63: all 64 waves' part-stores are at the MALL.
  __builtin_amdgcn_fence(__ATOMIC_ACQUIRE, "workgroup");
  const int lane = tid & 63;
  if (lane == 0)
    __hip_atomic_store(&g_cnt[b], 0, __ATOMIC_RELAXED,
                       __HIP_MEMORY_SCOPE_AGENT);  // clean for next replay

  // Two shapelets per lane: n = lane and lane+64.
  float m0 = FLT_MAX, m1 = FLT_MAX;
  {
    const float* pb = part + (size_t)b * NC * N + lane;
#pragma unroll
    for (int cc = 0; cc < NC; ++cc) {
      // For fixed cc, 64 lanes read consecutive floats -> coalesced; agent
      // scope bypasses this XCD's (possibly stale) L1/L2.
      float p0 = __hip_atomic_load(pb + cc * N, __ATOMIC_RELAXED,
                                   __HIP_MEMORY_SCOPE_AGENT);
      float p1 = __hip_atomic_load(pb + cc * N + 64, __ATOMIC_RELAXED,
                                   __HIP_MEMORY_SCOPE_AGENT);
      m0 = fminf(m0, p0);
      m1 = fminf(m1, p1);
    }
  }

  // ||s_n||^2 for both rows (shp is L2-hot; plain cached loads are fine —
  // shapelets are never written).
  float sn0 = 0.f, sn1 = 0.f;
  {
    const float4* sg0 = (const float4*)(shp + (size_t)lane * L);
    const float4* sg1 = (const float4*)(shp + (size_t)(lane + 64) * L);
#pragma unroll
    for (int i = 0; i < L / 4; ++i) {
      float4 a = sg0[i], bq = sg1[i];
      sn0 = fmaf(a.x, a.x, sn0);  sn0 = fmaf(a.y, a.y, sn0);
      sn0 = fmaf(a.z, a.z, sn0);  sn0 = fmaf(a.w, a.w, sn0);
      sn1 = fmaf(bq.x, bq.x, sn1); sn1 = fmaf(bq.y, bq.y, sn1);
      sn1 = fmaf(bq.z, bq.z, sn1); sn1 = fmaf(bq.w, bq.w, sn1);
    }
  }

  float v = sqrtf(fmaxf(m0 + sn0, 0.f)) * cls_w[lane] +
            sqrtf(fmaxf(m1 + sn1, 0.f)) * cls_w[lane + 64];
#pragma unroll
  for (int off = 32; off > 0; off >>= 1) v += __shfl_down(v, off, 64);
  if (lane == 0) {
    float z = v + cls_b[0];
    out[b] = 1.0f / (1.0f + expf(-z));
  }
}

extern "C" void kernel_launch(void* const* d_in, const int* in_sizes, int n_in,
                              void* d_out, int out_size, void* d_ws,
                              size_t ws_size, hipStream_t stream) {
  const float* x = (const float*)d_in[0];      // [B, W, L]
  const float* shp = (const float*)d_in[1];    // [N, L]
  const float* cls_w = (const float*)d_in[2];  // [1, N]
  const float* cls_b = (const float*)d_in[3];  // [1]
  float* out = (float*)d_out;                  // [B, 1]
  float* part = (float*)d_ws;                  // [B, NC, N] fp32 (512 KB)

  shapelet_fused_kernel<<<B * NC, 256, 0, stream>>>(x, shp, cls_w, cls_b,
                                                    part, out);
}

// Round 5
// 70.065 us; speedup vs baseline: 1.2678x; 1.2678x over previous
//
#include <hip/hip_runtime.h>
#include <cfloat>
#include <cmath>

// x[B,W,L], shapelets[N,L], cls_w[1,N], cls_b[1]
constexpr int B = 64;
constexpr int W = 256;
constexpr int N = 128;
constexpr int L = 64;
constexpr int NC = 16;        // window-chunks per batch element
constexpr int WPB = W / NC;   // 16 windows per block

// Arrival counters, ONE 128-BYTE CACHE LINE PER b.
// R2->R3->R4 dose-response (1024/2048/4096 arrival atomics -> 68.8/78.0/88.8
// us) showed ~10us per extra 1024 agent-scope RMWs: all counters shared 2-4
// cache lines, and same-line RMWs serialize at the coherent point. Padding
// gives each b a private line: 16 RMWs/line instead of ~1024+.
// Zero-initialized at module load (NOT in the poisoned workspace); last block
// restores 0 for the next graph replay (R2-verified under graph capture +
// rocprof counter replay).
struct __align__(128) PaddedCnt { int v; int pad[31]; };
__device__ PaddedCnt g_cnt[B];

// VALU-pipe cross-lane add (DPP), avoiding the DS pipe entirely.
// CTRL: 0xB1 = quad_perm xor1, 0x4E = quad_perm xor2,
//       0x141 = row_half_mirror (xor-4 class), 0x140 = row_mirror (xor-8).
template <int CTRL>
__device__ __forceinline__ float dpp_add(float v) {
  return v + __int_as_float(__builtin_amdgcn_update_dpp(
                 0, __float_as_int(v), CTRL, 0xF, 0xF, true));
}

// ---------------------------------------------------------------------------
// FUSED kernel, round 5 = EXACT R2 structure (proven 68.8us: per-block
// barrier'd arrival, last-block 256-thread head) + two surgical deltas:
//   (1) g_cnt padded to one cache line per b  (the R2-R4 contention fix),
//   (2) q-tree deleted; tail adds ||s_n||^2 once per b (sound part of R3/R4).
// Hot loop is the proven one: 8-lane groups x 4 shapelets, 2 ds_read_b128 +
// 56 VALU per wave per window, SQ_LDS_BANK_CONFLICT = 0, spill-free.
// grid = B*NC = 1024, block = 256 (4 blocks/CU).
// ---------------------------------------------------------------------------
__global__ __launch_bounds__(256)
void shapelet_fused_kernel(const float* __restrict__ x,
                           const float* __restrict__ shp,
                           const float* __restrict__ cls_w,
                           const float* __restrict__ cls_b,
                           float* __restrict__ part,
                           float* __restrict__ out) {
  __shared__ float xs[WPB * L];   // 4 KB
  __shared__ float xnorm_s[WPB];
  __shared__ int s_last;
  __shared__ float red[2];

  const int b = blockIdx.x >> 4;
  const int c = blockIdx.x & 15;
  const int tid = threadIdx.x;
  const int oct = tid & 7;        // eighth-of-row owned by this lane
  const int grp = tid >> 3;       // 0..31 -> shapelets 4*grp..4*grp+3
  const int n0 = grp * 4;

  // --- Stage x[b, c*16:(c+1)*16, :]: one float4/thread; ||x_w||^2 via a
  // 16-lane DPP reduction — zero DS-pipe swizzles.
  {
    const float4* xg =
        (const float4*)(x + ((size_t)b * W + (size_t)c * WPB) * L);
    float4 v = xg[tid];
    ((float4*)xs)[tid] = v;
    float p = v.x * v.x + v.y * v.y + v.z * v.z + v.w * v.w;
    p = dpp_add<0xB1>(p);    // xor1 (quad)
    p = dpp_add<0x4E>(p);    // xor2 (quad)
    p = dpp_add<0x141>(p);   // 4<->8 within row of 16
    p = dpp_add<0x140>(p);   // mirror row of 16
    if ((tid & 15) == 0) xnorm_s[tid >> 4] = p;
  }

  // --- Eighth-rows of 4 shapelets: 8 NAMED float4 (32 VGPRs). No arrays,
  // no q-tree (||s||^2 lives in the tail, once per b).
  const float4* g0 = (const float4*)(shp + (size_t)(n0 + 0) * L + oct * 8);
  const float4* g1 = (const float4*)(shp + (size_t)(n0 + 1) * L + oct * 8);
  const float4* g2 = (const float4*)(shp + (size_t)(n0 + 2) * L + oct * 8);
  const float4* g3 = (const float4*)(shp + (size_t)(n0 + 3) * L + oct * 8);
  const float4 s0a = g0[0], s0b = g0[1];
  const float4 s1a = g1[0], s1b = g1[1];
  const float4 s2a = g2[0], s2b = g2[1];
  const float4 s3a = g3[0], s3b = g3[1];

  __syncthreads();

  // --- min over all 16 windows of (xnorm_w - 2*dot(x_w, s_n)).
  float best0 = FLT_MAX, best1 = FLT_MAX, best2 = FLT_MAX, best3 = FLT_MAX;
  for (int w = 0; w < WPB; ++w) {
    const float4* xr = (const float4*)(xs + (size_t)w * L + oct * 8);
    const float4 xa = xr[0];
    const float4 xb = xr[1];

    float d0 = xa.x * s0a.x + xa.y * s0a.y;
    float d1 = xa.x * s1a.x + xa.y * s1a.y;
    float d2 = xa.x * s2a.x + xa.y * s2a.y;
    float d3 = xa.x * s3a.x + xa.y * s3a.y;
    d0 = fmaf(xa.z, s0a.z, d0); d0 = fmaf(xa.w, s0a.w, d0);
    d1 = fmaf(xa.z, s1a.z, d1); d1 = fmaf(xa.w, s1a.w, d1);
    d2 = fmaf(xa.z, s2a.z, d2); d2 = fmaf(xa.w, s2a.w, d2);
    d3 = fmaf(xa.z, s3a.z, d3); d3 = fmaf(xa.w, s3a.w, d3);
    d0 = fmaf(xb.x, s0b.x, d0); d0 = fmaf(xb.y, s0b.y, d0);
    d1 = fmaf(xb.x, s1b.x, d1); d1 = fmaf(xb.y, s1b.y, d1);
    d2 = fmaf(xb.x, s2b.x, d2); d2 = fmaf(xb.y, s2b.y, d2);
    d3 = fmaf(xb.x, s3b.x, d3); d3 = fmaf(xb.y, s3b.y, d3);
    d0 = fmaf(xb.z, s0b.z, d0); d0 = fmaf(xb.w, s0b.w, d0);
    d1 = fmaf(xb.z, s1b.z, d1); d1 = fmaf(xb.w, s1b.w, d1);
    d2 = fmaf(xb.z, s2b.z, d2); d2 = fmaf(xb.w, s2b.w, d2);
    d3 = fmaf(xb.z, s3b.z, d3); d3 = fmaf(xb.w, s3b.w, d3);

    d0 = dpp_add<0xB1>(d0);  d1 = dpp_add<0xB1>(d1);
    d2 = dpp_add<0xB1>(d2);  d3 = dpp_add<0xB1>(d3);
    d0 = dpp_add<0x4E>(d0);  d1 = dpp_add<0x4E>(d1);
    d2 = dpp_add<0x4E>(d2);  d3 = dpp_add<0x4E>(d3);
    d0 = dpp_add<0x141>(d0); d1 = dpp_add<0x141>(d1);
    d2 = dpp_add<0x141>(d2); d3 = dpp_add<0x141>(d3);

    const float xn = xnorm_s[w];
    best0 = fminf(best0, fmaf(-2.f, d0, xn));
    best1 = fminf(best1, fmaf(-2.f, d1, xn));
    best2 = fminf(best2, fmaf(-2.f, d2, xn));
    best3 = fminf(best3, fmaf(-2.f, d3, xn));
  }

  // --- oct-leader writes 4 chunk-mins (xnorm - 2dot; ||s||^2 added in tail)
  // as AGENT-scope (sc1) write-through stores: cross-XCD visible with no
  // cache-maintenance instructions (R2-verified protocol).
  if (oct == 0) {
    float* p = part + ((size_t)b * NC + c) * N + n0;
    __hip_atomic_store(p + 0, best0, __ATOMIC_RELAXED,
                       __HIP_MEMORY_SCOPE_AGENT);
    __hip_atomic_store(p + 1, best1, __ATOMIC_RELAXED,
                       __HIP_MEMORY_SCOPE_AGENT);
    __hip_atomic_store(p + 2, best2, __ATOMIC_RELAXED,
                       __HIP_MEMORY_SCOPE_AGENT);
    __hip_atomic_store(p + 3, best3, __ATOMIC_RELAXED,
                       __HIP_MEMORY_SCOPE_AGENT);
  }

  // --- Arrival (R2 protocol): __syncthreads() emits s_waitcnt vmcnt(0) in
  // every wave, so all sc1 part-stores are at the agent-coherent point before
  // tid0's relaxed agent arrival add. ONE atomic per block, on this b's
  // PRIVATE cache line.
  __syncthreads();
  if (tid == 0) {
    int done = __hip_atomic_fetch_add(&g_cnt[b].v, 1, __ATOMIC_RELAXED,
                                      __HIP_MEMORY_SCOPE_AGENT);
    s_last = (done == NC - 1) ? 1 : 0;
    if (done == NC - 1)
      __hip_atomic_store(&g_cnt[b].v, 0, __ATOMIC_RELAXED,
                         __HIP_MEMORY_SCOPE_AGENT);  // clean for next replay
  }
  __syncthreads();
  if (!s_last) return;

  // --- Last block for this b: classifier head. All 256 threads alive
  // (uniform branch on shared s_last) so the barrier below is safe.
  // part reads are agent-scope loads (bypass stale L1/L2); for fixed cc,
  // lanes read consecutive n -> coalesced.
  float v = 0.f;
  if (tid < N) {
    const float* pb = part + (size_t)b * NC * N + tid;
    float m = FLT_MAX;
#pragma unroll
    for (int cc = 0; cc < NC; ++cc) {
      float pv = __hip_atomic_load(pb + cc * N, __ATOMIC_RELAXED,
                                   __HIP_MEMORY_SCOPE_AGENT);
      m = fminf(m, pv);
    }
    // ||s_n||^2 once per b (shp is L2-hot; read-only data, plain loads).
    float sn = 0.f;
    const float4* sg = (const float4*)(shp + (size_t)tid * L);
#pragma unroll
    for (int i = 0; i < L / 4; ++i) {
      float4 s = sg[i];
      sn = fmaf(s.x, s.x, sn);
      sn = fmaf(s.y, s.y, sn);
      sn = fmaf(s.z, s.z, sn);
      sn = fmaf(s.w, s.w, sn);
    }
    float d2 = fmaxf(m + sn, 0.f);  // guard fp rounding before sqrt
    v = sqrtf(d2) * cls_w[tid];
  }
#pragma unroll
  for (int off = 32; off > 0; off >>= 1) v += __shfl_down(v, off, 64);
  if ((tid & 63) == 0) red[tid >> 6] = v;
  __syncthreads();
  if (tid == 0) {
    float z = red[0] + red[1] + cls_b[0];
    out[b] = 1.0f / (1.0f + expf(-z));
  }
}

extern "C" void kernel_launch(void* const* d_in, const int* in_sizes, int n_in,
                              void* d_out, int out_size, void* d_ws,
                              size_t ws_size, hipStream_t stream) {
  const float* x = (const float*)d_in[0];      // [B, W, L]
  const float* shp = (const float*)d_in[1];    // [N, L]
  const float* cls_w = (const float*)d_in[2];  // [1, N]
  const float* cls_b = (const float*)d_in[3];  // [1]
  float* out = (float*)d_out;                  // [B, 1]
  float* part = (float*)d_ws;                  // [B, NC, N] fp32 (512 KB)

  shapelet_fused_kernel<<<B * NC, 256, 0, stream>>>(x, shp, cls_w, cls_b,
                                                    part, out);
}

// Round 6
// 67.253 us; speedup vs baseline: 1.3209x; 1.0418x over previous
//
#include <hip/hip_runtime.h>
#include <cfloat>
#include <cmath>

// x[B,W,L], shapelets[N,L], cls_w[1,N], cls_b[1]
constexpr int B = 64;
constexpr int W = 256;
constexpr int N = 128;
constexpr int L = 64;
constexpr int NC = 16;        // window-chunks per batch element
constexpr int WPB = W / NC;   // 16 windows per block

// Arrival counters, one 128-byte line per b (R5: neutral vs shared lines,
// kept because it is sound and free). Zero-initialized at module load; last
// block restores 0 for the next graph replay (R2-verified under graph
// capture + rocprof counter replay).
struct __align__(128) PaddedCnt { int v; int pad[31]; };
__device__ PaddedCnt g_cnt[B];

// VALU-pipe cross-lane add (DPP), avoiding the DS pipe entirely.
// CTRL: 0xB1 = quad_perm xor1, 0x4E = quad_perm xor2,
//       0x141 = row_half_mirror (xor-4 class), 0x140 = row_mirror (xor-8).
template <int CTRL>
__device__ __forceinline__ float dpp_add(float v) {
  return v + __int_as_float(__builtin_amdgcn_update_dpp(
                 0, __float_as_int(v), CTRL, 0xF, 0xF, true));
}

// ---------------------------------------------------------------------------
// FUSED kernel, round 6. Ledger after R5: three structurally different
// kernels all land 68.8-70.1; fixed harness cost = fill(40.6) + gaps(~6.8);
// inferred fused-kernel time ~21us vs ~8-9us issue arithmetic -> latency/
// clock-bound, with only 4 independent accumulation chains per wave.
//
// This round's single change: 2 WINDOWS PER ITERATION (w and w+8) -> 8
// independent dot chains per wave, half the loop-control, same FMA/DPP/DS
// totals (+~24 VGPR, still 4 blocks/CU). Shapelet loads issued before
// x-staging to overlap prologue latency. Epilogue = R5's proven one.
// This is the discriminating experiment for the latency theory: if dur
// doesn't move, the kernel is at its practical floor.
// grid = B*NC = 1024, block = 256 (4 blocks/CU).
// ---------------------------------------------------------------------------
__global__ __launch_bounds__(256)
void shapelet_fused_kernel(const float* __restrict__ x,
                           const float* __restrict__ shp,
                           const float* __restrict__ cls_w,
                           const float* __restrict__ cls_b,
                           float* __restrict__ part,
                           float* __restrict__ out) {
  __shared__ float xs[WPB * L];   // 4 KB
  __shared__ float xnorm_s[WPB];
  __shared__ int s_last;
  __shared__ float red[2];

  const int b = blockIdx.x >> 4;
  const int c = blockIdx.x & 15;
  const int tid = threadIdx.x;
  const int oct = tid & 7;        // eighth-of-row owned by this lane
  const int grp = tid >> 3;       // 0..31 -> shapelets 4*grp..4*grp+3
  const int n0 = grp * 4;

  // --- Issue shapelet loads FIRST so their HBM/L2 latency overlaps the
  // x-staging below (8 named float4 = 32 VGPRs, no arrays).
  const float4* g0 = (const float4*)(shp + (size_t)(n0 + 0) * L + oct * 8);
  const float4* g1 = (const float4*)(shp + (size_t)(n0 + 1) * L + oct * 8);
  const float4* g2 = (const float4*)(shp + (size_t)(n0 + 2) * L + oct * 8);
  const float4* g3 = (const float4*)(shp + (size_t)(n0 + 3) * L + oct * 8);
  const float4 s0a = g0[0], s0b = g0[1];
  const float4 s1a = g1[0], s1b = g1[1];
  const float4 s2a = g2[0], s2b = g2[1];
  const float4 s3a = g3[0], s3b = g3[1];

  // --- Stage x[b, c*16:(c+1)*16, :]: one float4/thread; ||x_w||^2 via a
  // 16-lane DPP reduction — zero DS-pipe swizzles.
  {
    const float4* xg =
        (const float4*)(x + ((size_t)b * W + (size_t)c * WPB) * L);
    float4 v = xg[tid];
    ((float4*)xs)[tid] = v;
    float p = v.x * v.x + v.y * v.y + v.z * v.z + v.w * v.w;
    p = dpp_add<0xB1>(p);    // xor1 (quad)
    p = dpp_add<0x4E>(p);    // xor2 (quad)
    p = dpp_add<0x141>(p);   // 4<->8 within row of 16
    p = dpp_add<0x140>(p);   // mirror row of 16
    if ((tid & 15) == 0) xnorm_s[tid >> 4] = p;
  }

  __syncthreads();

  // --- min over 16 windows of (xnorm_w - 2*dot(x_w, s_n)), TWO windows per
  // iteration (w and w+8): 8 independent accumulation chains per wave.
  float best0 = FLT_MAX, best1 = FLT_MAX, best2 = FLT_MAX, best3 = FLT_MAX;
  for (int w = 0; w < WPB / 2; ++w) {
    const float4* xr0 = (const float4*)(xs + (size_t)w * L + oct * 8);
    const float4* xr1 = (const float4*)(xs + (size_t)(w + 8) * L + oct * 8);
    const float4 xa = xr0[0];
    const float4 xb = xr0[1];
    const float4 ya = xr1[0];
    const float4 yb = xr1[1];

    // Window w -> d0..d3
    float d0 = xa.x * s0a.x + xa.y * s0a.y;
    float d1 = xa.x * s1a.x + xa.y * s1a.y;
    float d2 = xa.x * s2a.x + xa.y * s2a.y;
    float d3 = xa.x * s3a.x + xa.y * s3a.y;
    // Window w+8 -> e0..e3 (independent chains, interleaved by the compiler)
    float e0 = ya.x * s0a.x + ya.y * s0a.y;
    float e1 = ya.x * s1a.x + ya.y * s1a.y;
    float e2 = ya.x * s2a.x + ya.y * s2a.y;
    float e3 = ya.x * s3a.x + ya.y * s3a.y;

    d0 = fmaf(xa.z, s0a.z, d0); d0 = fmaf(xa.w, s0a.w, d0);
    d1 = fmaf(xa.z, s1a.z, d1); d1 = fmaf(xa.w, s1a.w, d1);
    d2 = fmaf(xa.z, s2a.z, d2); d2 = fmaf(xa.w, s2a.w, d2);
    d3 = fmaf(xa.z, s3a.z, d3); d3 = fmaf(xa.w, s3a.w, d3);
    e0 = fmaf(ya.z, s0a.z, e0); e0 = fmaf(ya.w, s0a.w, e0);
    e1 = fmaf(ya.z, s1a.z, e1); e1 = fmaf(ya.w, s1a.w, e1);
    e2 = fmaf(ya.z, s2a.z, e2); e2 = fmaf(ya.w, s2a.w, e2);
    e3 = fmaf(ya.z, s3a.z, e3); e3 = fmaf(ya.w, s3a.w, e3);

    d0 = fmaf(xb.x, s0b.x, d0); d0 = fmaf(xb.y, s0b.y, d0);
    d1 = fmaf(xb.x, s1b.x, d1); d1 = fmaf(xb.y, s1b.y, d1);
    d2 = fmaf(xb.x, s2b.x, d2); d2 = fmaf(xb.y, s2b.y, d2);
    d3 = fmaf(xb.x, s3b.x, d3); d3 = fmaf(xb.y, s3b.y, d3);
    e0 = fmaf(yb.x, s0b.x, e0); e0 = fmaf(yb.y, s0b.y, e0);
    e1 = fmaf(yb.x, s1b.x, e1); e1 = fmaf(yb.y, s1b.y, e1);
    e2 = fmaf(yb.x, s2b.x, e2); e2 = fmaf(yb.y, s2b.y, e2);
    e3 = fmaf(yb.x, s3b.x, e3); e3 = fmaf(yb.y, s3b.y, e3);

    d0 = fmaf(xb.z, s0b.z, d0); d0 = fmaf(xb.w, s0b.w, d0);
    d1 = fmaf(xb.z, s1b.z, d1); d1 = fmaf(xb.w, s1b.w, d1);
    d2 = fmaf(xb.z, s2b.z, d2); d2 = fmaf(xb.w, s2b.w, d2);
    d3 = fmaf(xb.z, s3b.z, d3); d3 = fmaf(xb.w, s3b.w, d3);
    e0 = fmaf(yb.z, s0b.z, e0); e0 = fmaf(yb.w, s0b.w, e0);
    e1 = fmaf(yb.z, s1b.z, e1); e1 = fmaf(yb.w, s1b.w, e1);
    e2 = fmaf(yb.z, s2b.z, e2); e2 = fmaf(yb.w, s2b.w, e2);
    e3 = fmaf(yb.z, s3b.z, e3); e3 = fmaf(yb.w, s3b.w, e3);

    // 8-lane reductions — 8 independent 3-stage DPP trees.
    d0 = dpp_add<0xB1>(d0);  d1 = dpp_add<0xB1>(d1);
    d2 = dpp_add<0xB1>(d2);  d3 = dpp_add<0xB1>(d3);
    e0 = dpp_add<0xB1>(e0);  e1 = dpp_add<0xB1>(e1);
    e2 = dpp_add<0xB1>(e2);  e3 = dpp_add<0xB1>(e3);
    d0 = dpp_add<0x4E>(d0);  d1 = dpp_add<0x4E>(d1);
    d2 = dpp_add<0x4E>(d2);  d3 = dpp_add<0x4E>(d3);
    e0 = dpp_add<0x4E>(e0);  e1 = dpp_add<0x4E>(e1);
    e2 = dpp_add<0x4E>(e2);  e3 = dpp_add<0x4E>(e3);
    d0 = dpp_add<0x141>(d0); d1 = dpp_add<0x141>(d1);
    d2 = dpp_add<0x141>(d2); d3 = dpp_add<0x141>(d3);
    e0 = dpp_add<0x141>(e0); e1 = dpp_add<0x141>(e1);
    e2 = dpp_add<0x141>(e2); e3 = dpp_add<0x141>(e3);

    const float xn0 = xnorm_s[w];
    const float xn1 = xnorm_s[w + 8];
    // fminf(fminf(a,b),c) -> v_min3_f32 candidates for the compiler.
    best0 = fminf(fminf(best0, fmaf(-2.f, d0, xn0)), fmaf(-2.f, e0, xn1));
    best1 = fminf(fminf(best1, fmaf(-2.f, d1, xn0)), fmaf(-2.f, e1, xn1));
    best2 = fminf(fminf(best2, fmaf(-2.f, d2, xn0)), fmaf(-2.f, e2, xn1));
    best3 = fminf(fminf(best3, fmaf(-2.f, d3, xn0)), fmaf(-2.f, e3, xn1));
  }

  // --- oct-leader writes 4 chunk-mins (xnorm - 2dot; ||s||^2 added in tail)
  // as AGENT-scope (sc1) write-through stores: cross-XCD visible with no
  // cache-maintenance instructions (R2-verified protocol).
  if (oct == 0) {
    float* p = part + ((size_t)b * NC + c) * N + n0;
    __hip_atomic_store(p + 0, best0, __ATOMIC_RELAXED,
                       __HIP_MEMORY_SCOPE_AGENT);
    __hip_atomic_store(p + 1, best1, __ATOMIC_RELAXED,
                       __HIP_MEMORY_SCOPE_AGENT);
    __hip_atomic_store(p + 2, best2, __ATOMIC_RELAXED,
                       __HIP_MEMORY_SCOPE_AGENT);
    __hip_atomic_store(p + 3, best3, __ATOMIC_RELAXED,
                       __HIP_MEMORY_SCOPE_AGENT);
  }

  // --- Arrival (R2 protocol): __syncthreads() emits s_waitcnt vmcnt(0) in
  // every wave, so all sc1 part-stores are at the agent-coherent point before
  // tid0's relaxed agent arrival add. One atomic per block, private line.
  __syncthreads();
  if (tid == 0) {
    int done = __hip_atomic_fetch_add(&g_cnt[b].v, 1, __ATOMIC_RELAXED,
                                      __HIP_MEMORY_SCOPE_AGENT);
    s_last = (done == NC - 1) ? 1 : 0;
    if (done == NC - 1)
      __hip_atomic_store(&g_cnt[b].v, 0, __ATOMIC_RELAXED,
                         __HIP_MEMORY_SCOPE_AGENT);  // clean for next replay
  }
  __syncthreads();
  if (!s_last) return;

  // --- Last block for this b: classifier head (min over chunks + ||s_n||^2
  // + sqrt + dot + sigmoid). All 256 threads alive (uniform branch on shared
  // s_last) so the barrier below is safe. part reads are agent-scope loads
  // (bypass stale L1/L2); for fixed cc, lanes read consecutive n ->
  // coalesced.
  float v = 0.f;
  if (tid < N) {
    const float* pb = part + (size_t)b * NC * N + tid;
    float m = FLT_MAX;
#pragma unroll
    for (int cc = 0; cc < NC; ++cc) {
      float pv = __hip_atomic_load(pb + cc * N, __ATOMIC_RELAXED,
                                   __HIP_MEMORY_SCOPE_AGENT);
      m = fminf(m, pv);
    }
    // ||s_n||^2 once per b (shp is L2-hot; read-only data, plain loads).
    float sn = 0.f;
    const float4* sg = (const float4*)(shp + (size_t)tid * L);
#pragma unroll
    for (int i = 0; i < L / 4; ++i) {
      float4 s = sg[i];
      sn = fmaf(s.x, s.x, sn);
      sn = fmaf(s.y, s.y, sn);
      sn = fmaf(s.z, s.z, sn);
      sn = fmaf(s.w, s.w, sn);
    }
    float d2 = fmaxf(m + sn, 0.f);  // guard fp rounding before sqrt
    v = sqrtf(d2) * cls_w[tid];
  }
#pragma unroll
  for (int off = 32; off > 0; off >>= 1) v += __shfl_down(v, off, 64);
  if ((tid & 63) == 0) red[tid >> 6] = v;
  __syncthreads();
  if (tid == 0) {
    float z = red[0] + red[1] + cls_b[0];
    out[b] = 1.0f / (1.0f + expf(-z));
  }
}

extern "C" void kernel_launch(void* const* d_in, const int* in_sizes, int n_in,
                              void* d_out, int out_size, void* d_ws,
                              size_t ws_size, hipStream_t stream) {
  const float* x = (const float*)d_in[0];      // [B, W, L]
  const float* shp = (const float*)d_in[1];    // [N, L]
  const float* cls_w = (const float*)d_in[2];  // [1, N]
  const float* cls_b = (const float*)d_in[3];  // [1]
  float* out = (float*)d_out;                  // [B, 1]
  float* part = (float*)d_ws;                  // [B, NC, N] fp32 (512 KB)

  shapelet_fused_kernel<<<B * NC, 256, 0, stream>>>(x, shp, cls_w, cls_b,
                                                    part, out);
}